// Round 10
// baseline (233.835 us; speedup 1.0000x reference)
//
#include <hip/hip_runtime.h>
#include <stdint.h>

// Problem constants
#define DM 512
#define NH 8
#define HDIM 64
#define TT 4096
#define PP 1024

typedef float f32x4 __attribute__((ext_vector_type(4)));
typedef __bf16 bf16x8 __attribute__((ext_vector_type(8)));
typedef unsigned short u16x8 __attribute__((ext_vector_type(8)));
typedef unsigned short u16x4 __attribute__((ext_vector_type(4)));
typedef unsigned int u32x2 __attribute__((ext_vector_type(2)));
typedef unsigned int u32x4 __attribute__((ext_vector_type(4)));

static __device__ __forceinline__ unsigned short f2bf(float f) {
  unsigned u = __builtin_bit_cast(unsigned, f);
  u += 0x7fff + ((u >> 16) & 1);  // RNE
  return (unsigned short)(u >> 16);
}

// pack two floats -> bf16 pair (round-half-up): low u16 = bf(a), high = bf(b)
static __device__ __forceinline__ unsigned packrnd(float a, float b) {
  unsigned ua = __builtin_bit_cast(unsigned, a) + 0x8000u;
  unsigned ub = __builtin_bit_cast(unsigned, b) + 0x8000u;
  return __builtin_amdgcn_perm(ub, ua, 0x07060302u);
}
// truncating pack (for P: bias cancels in sum(Pv)/sum(P))
static __device__ __forceinline__ unsigned packtr(float a, float b) {
  return __builtin_amdgcn_perm(__builtin_bit_cast(unsigned, b),
                               __builtin_bit_cast(unsigned, a), 0x07060302u);
}

static __device__ __forceinline__ float fexp2(float x) {
#if __has_builtin(__builtin_amdgcn_exp2f)
  return __builtin_amdgcn_exp2f(x);
#else
  return __expf(x * 0.69314718055994531f);
#endif
}

static __device__ __forceinline__ void load_lds16(const void* g, void* l) {
  __builtin_amdgcn_global_load_lds(
      (__attribute__((address_space(1))) void*)g,
      (__attribute__((address_space(3))) void*)l, 16, 0, 0);
}

static __device__ __forceinline__ f32x4 mfma16(bf16x8 a, bf16x8 b, f32x4 c) {
  return __builtin_amdgcn_mfma_f32_16x16x32_bf16(a, b, c, 0, 0, 0);
}

// ---------------------------------------------------------------------------
// Weight transpose+convert: W[k][n] fp32 -> Wt[n][k] bf16, 4 matrices.
// ---------------------------------------------------------------------------
__global__ __launch_bounds__(256) void k_wconv(
    const float* __restrict__ wq, const float* __restrict__ wk,
    const float* __restrict__ wv, const float* __restrict__ wo,
    unsigned short* __restrict__ wt) {
  const int wi = blockIdx.x * 256 + threadIdx.x;  // [0, 262144)
  const int wid = wi >> 16;                       // 0..3 -> q,k,v,o
  const int e = (wi & 65535) << 2;                // element index k*512+n
  const int k = e >> 9, n = e & 511;
  const float* w = (wid == 0) ? wq : (wid == 1) ? wk : (wid == 2) ? wv : wo;
  f32x4 v = *(const f32x4*)&w[e];
  unsigned short* wtb = wt + (wid << 18);
#pragma unroll
  for (int i = 0; i < 4; ++i) wtb[(n + i) * 512 + k] = f2bf(v[i]);
}

// ---------------------------------------------------------------------------
// Projection GEMM, 128x128 tile. A path goes GLOBAL->REGS->MFMA (per-lane
// fragment loads + in-register bf16 pack) — no A LDS round-trip, so the
// single barrier per K-iter guards only the double-buffered B DMA.
//   MODE 0: bf16 row-major (Q, scale folds 1/sqrt(HD) * log2(e))
//   MODE 1: bf16 row-major (K)
//   MODE 2: bf16 transposed to VT[b][n][p] (V)
// ---------------------------------------------------------------------------
template <int MODE>
__device__ __forceinline__ void gemm_fp32_body(
    const float* __restrict__ A, const unsigned short* __restrict__ Wt,
    const float* __restrict__ bias, unsigned short* __restrict__ outb,
    int bid, unsigned short* sB, float scale) {
  const int tid = threadIdx.x;
  const int wave = tid >> 6, lane = tid & 63;
  const int q = lane >> 4, c = lane & 15;
  const int bm = bid >> 2, bn = bid & 3;
  const int wm = (wave >> 1) * 64, wn = (wave & 1) * 64;
  const int lr = lane >> 2, lc = (lane & 3) * 8;

  f32x4 acc[4][4];
#pragma unroll
  for (int i = 0; i < 4; ++i)
#pragma unroll
    for (int j = 0; j < 4; ++j) acc[i][j] = (f32x4){0.f, 0.f, 0.f, 0.f};

  const int rowA0 = bm * 128, rowB0 = bn * 128;

  // per-lane A fragment row pointers (m = wm+mt*16+c, k base = q*8)
  const float* arow[4];
#pragma unroll
  for (int mt = 0; mt < 4; ++mt)
    arow[mt] = A + (rowA0 + wm + mt * 16 + c) * 512 + q * 8;

  f32x4 a0[4], a1[4];
  // prologue: A(0) into regs; B(0) DMA into buf 0
#pragma unroll
  for (int mt = 0; mt < 4; ++mt) {
    a0[mt] = *(const f32x4*)(arow[mt]);
    a1[mt] = *(const f32x4*)(arow[mt] + 4);
  }
#pragma unroll
  for (int qq = 0; qq < 2; ++qq) {
    const int row = (wave * 2 + qq) * 16 + lr;
    load_lds16(&Wt[(rowB0 + row) * 512 + lc], &sB[(wave * 2 + qq) * 512]);
  }
  __syncthreads();

#pragma unroll 1
  for (int i = 0; i < 16; ++i) {
    const int buf = i & 1;
    const unsigned short* curB = sB + buf * 4096;
    unsigned short* nxtB = sB + (buf ^ 1) * 4096;
    const bool more = (i < 15);
    const int kn = (i + 1) * 32;
    if (more) {  // B DMA for k(i+1) into the other buffer
#pragma unroll
      for (int qq = 0; qq < 2; ++qq) {
        const int row = (wave * 2 + qq) * 16 + lr;
        load_lds16(&Wt[(rowB0 + row) * 512 + kn + lc], &nxtB[(wave * 2 + qq) * 512]);
      }
    }
    // pack A(i) regs -> MFMA operands
    bf16x8 af[4];
#pragma unroll
    for (int mt = 0; mt < 4; ++mt) {
      u32x4 pk;
      pk[0] = packrnd(a0[mt][0], a0[mt][1]);
      pk[1] = packrnd(a0[mt][2], a0[mt][3]);
      pk[2] = packrnd(a1[mt][0], a1[mt][1]);
      pk[3] = packrnd(a1[mt][2], a1[mt][3]);
      af[mt] = __builtin_bit_cast(bf16x8, pk);
    }
    if (more) {  // prefetch A(i+1) into regs (covered by MFMA + barrier)
#pragma unroll
      for (int mt = 0; mt < 4; ++mt) {
        a0[mt] = *(const f32x4*)(arow[mt] + kn);
        a1[mt] = *(const f32x4*)(arow[mt] + kn + 4);
      }
    }
    bf16x8 bfr[4];
#pragma unroll
    for (int nt = 0; nt < 4; ++nt)
      bfr[nt] = __builtin_bit_cast(bf16x8, *(const u16x8*)&curB[(wn + nt * 16 + c) * 32 + q * 8]);
#pragma unroll
    for (int mt = 0; mt < 4; ++mt)
#pragma unroll
      for (int nt = 0; nt < 4; ++nt)
        acc[mt][nt] = mfma16(af[mt], bfr[nt], acc[mt][nt]);
    if (more) __syncthreads();
  }

#pragma unroll
  for (int nt = 0; nt < 4; ++nt) {
    const int col = bn * 128 + wn + nt * 16 + c;
    const float bcol = bias[col];
#pragma unroll
    for (int mt = 0; mt < 4; ++mt) {
      const int row0 = bm * 128 + wm + mt * 16 + q * 4;
#pragma unroll
      for (int r = 0; r < 4; ++r) {
        const int row = row0 + r;
        const float v = (acc[mt][nt][r] + bcol) * scale;
        if (MODE == 2) {
          outb[((row >> 10) << 19) + (col << 10) + (row & 1023)] = f2bf(v);
        } else {
          outb[row * 512 + col] = f2bf(v);
        }
      }
    }
  }
}

__global__ __launch_bounds__(256) void k_gemm_qkv(
    const float* __restrict__ tok, const float* __restrict__ pat,
    const unsigned short* __restrict__ WT,
    const float* __restrict__ bq, const float* __restrict__ bk,
    const float* __restrict__ bv,
    unsigned short* __restrict__ QB, unsigned short* __restrict__ KB,
    unsigned short* __restrict__ VTB) {
  __shared__ unsigned short sB[2 * 128 * 32];
  const int bid = blockIdx.x;
  if (bid < 512) {
    // scale = 0.125 * log2(e): scores come out in log2 domain for exp2
    gemm_fp32_body<0>(tok, WT, bq, QB, bid, sB, 0.18033688011112042f);
  } else if (bid < 640) {
    gemm_fp32_body<1>(pat, WT + 262144, bk, KB, bid - 512, sB, 1.0f);
  } else {
    gemm_fp32_body<2>(pat, WT + 524288, bv, VTB, bid - 640, sB, 1.0f);
  }
}

// ---------------------------------------------------------------------------
// Out-projection GEMM, 128x128: out = CTX @ Wo + bo + resid (fp32).
// A (bf16) per-lane fragment loads direct to regs; B double-buffered DMA,
// one barrier per K-iter.
// ---------------------------------------------------------------------------
__global__ __launch_bounds__(256) void k_gemm_o(
    const unsigned short* __restrict__ A, const unsigned short* __restrict__ Wt,
    const float* __restrict__ bias, float* __restrict__ outf,
    const float* __restrict__ resid) {
  __shared__ unsigned short sB[2 * 128 * 32];
  const int tid = threadIdx.x;
  const int wave = tid >> 6, lane = tid & 63;
  const int q = lane >> 4, c = lane & 15;
  const int bm = blockIdx.x >> 2, bn = blockIdx.x & 3;
  const int wm = (wave >> 1) * 64, wn = (wave & 1) * 64;
  const int lr = lane >> 2, lc = (lane & 3) * 8;

  f32x4 acc[4][4];
#pragma unroll
  for (int i = 0; i < 4; ++i)
#pragma unroll
    for (int j = 0; j < 4; ++j) acc[i][j] = (f32x4){0.f, 0.f, 0.f, 0.f};

  const int rowA0 = bm * 128, rowB0 = bn * 128;

  const unsigned short* arow[4];
#pragma unroll
  for (int mt = 0; mt < 4; ++mt)
    arow[mt] = A + (rowA0 + wm + mt * 16 + c) * 512 + q * 8;

  u16x8 aw[4];
#pragma unroll
  for (int mt = 0; mt < 4; ++mt) aw[mt] = *(const u16x8*)(arow[mt]);
#pragma unroll
  for (int qq = 0; qq < 2; ++qq) {
    const int row = (wave * 2 + qq) * 16 + lr;
    load_lds16(&Wt[(rowB0 + row) * 512 + lc], &sB[(wave * 2 + qq) * 512]);
  }
  __syncthreads();

#pragma unroll 1
  for (int i = 0; i < 16; ++i) {
    const int buf = i & 1;
    const unsigned short* curB = sB + buf * 4096;
    unsigned short* nxtB = sB + (buf ^ 1) * 4096;
    const bool more = (i < 15);
    const int kn = (i + 1) * 32;
    if (more) {
#pragma unroll
      for (int qq = 0; qq < 2; ++qq) {
        const int row = (wave * 2 + qq) * 16 + lr;
        load_lds16(&Wt[(rowB0 + row) * 512 + kn + lc], &nxtB[(wave * 2 + qq) * 512]);
      }
    }
    bf16x8 af[4];
#pragma unroll
    for (int mt = 0; mt < 4; ++mt) af[mt] = __builtin_bit_cast(bf16x8, aw[mt]);
    if (more) {
#pragma unroll
      for (int mt = 0; mt < 4; ++mt) aw[mt] = *(const u16x8*)(arow[mt] + kn);
    }
    bf16x8 bfr[4];
#pragma unroll
    for (int nt = 0; nt < 4; ++nt)
      bfr[nt] = __builtin_bit_cast(bf16x8, *(const u16x8*)&curB[(wn + nt * 16 + c) * 32 + q * 8]);
#pragma unroll
    for (int mt = 0; mt < 4; ++mt)
#pragma unroll
      for (int nt = 0; nt < 4; ++nt)
        acc[mt][nt] = mfma16(af[mt], bfr[nt], acc[mt][nt]);
    if (more) __syncthreads();
  }

#pragma unroll
  for (int nt = 0; nt < 4; ++nt) {
    const int col = bn * 128 + wn + nt * 16 + c;
    const float bcol = bias[col];
#pragma unroll
    for (int mt = 0; mt < 4; ++mt) {
      const int row0 = bm * 128 + wm + mt * 16 + q * 4;
#pragma unroll
      for (int r = 0; r < 4; ++r) {
        const int row = row0 + r;
        const int o = row * 512 + col;
        outf[o] = acc[mt][nt][r] + bcol + resid[o];
      }
    }
  }
}

// ---------------------------------------------------------------------------
// Kernel 3: block-causal cross attention, no-max softmax in log2 domain.
// 1024 blocks, block = one (tg, b, h) unit (128 tokens), ntile = tg+1.
// Mapping g=bid>>5, tg = g<16 ? g : 47-g makes every stride-256 set
// {j, j+256, j+512, j+768} sum to exactly 66 tiles per CU (uniform);
// 4 blocks/CU = 16 waves/CU for latency hiding.
// ---------------------------------------------------------------------------
__global__ __launch_bounds__(256) void k_attn(
    const unsigned short* __restrict__ Q,   // [B*T][512], scaled by .125*log2e
    const unsigned short* __restrict__ K,   // [B*P][512]
    const unsigned short* __restrict__ VT,  // [B][512][1024]
    unsigned short* __restrict__ CTX) {     // [B*T][512]
  __shared__ unsigned short sK[2][32 * 88];
  __shared__ unsigned short sV[2][64 * 40];
  __shared__ unsigned short sPT[4][32 * 40];

  const int tid = threadIdx.x;
  const int lane = tid & 63;
  const int wave = tid >> 6;
  const int q = lane >> 4, c = lane & 15;

  const int g = blockIdx.x >> 5;               // [0,32)
  const int tg = (g < 16) ? g : 47 - g;        // uniform-per-CU mapping
  const int bh = blockIdx.x & 31;
  const int b = bh >> 3, h = bh & 7;
  const int t0 = tg * 128 + wave * 32;
  const int tA = t0 + c, tB = t0 + 16 + c;

  const int qbA = (b * TT + tA) * 512 + h * 64 + q * 8;
  const int qbB = (b * TT + tB) * 512 + h * 64 + q * 8;
  const bf16x8 qfA0 = __builtin_bit_cast(bf16x8, *(const u16x8*)&Q[qbA]);
  const bf16x8 qfA1 = __builtin_bit_cast(bf16x8, *(const u16x8*)&Q[qbA + 32]);
  const bf16x8 qfB0 = __builtin_bit_cast(bf16x8, *(const u16x8*)&Q[qbB]);
  const bf16x8 qfB1 = __builtin_bit_cast(bf16x8, *(const u16x8*)&Q[qbB + 32]);

  f32x4 oA[4], oB[4];
#pragma unroll
  for (int m = 0; m < 4; ++m) {
    oA[m] = (f32x4){0.f, 0.f, 0.f, 0.f};
    oB[m] = (f32x4){0.f, 0.f, 0.f, 0.f};
  }
  f32x4 lA = (f32x4){0.f, 0.f, 0.f, 0.f};
  f32x4 lB = lA;
  const u16x8 onesu = {0x3F80, 0x3F80, 0x3F80, 0x3F80, 0x3F80, 0x3F80, 0x3F80, 0x3F80};
  const bf16x8 ones = __builtin_bit_cast(bf16x8, onesu);

  const int ntile = tg + 1;
  const int krow = tid >> 3, kcol = (tid & 7) * 8;
  const int vrow = tid >> 2, vcol = (tid & 3) * 8;
  const int kg = (b * PP + krow) * 512 + h * 64 + kcol;
  const int vg = (b << 19) + ((h * 64 + vrow) << 10) + vcol;
  unsigned short* sp = sPT[wave];

  // stage tile 0
  u16x8 kreg = *(const u16x8*)&K[kg];
  u16x8 vreg = *(const u16x8*)&VT[vg];
  *(u16x8*)&sK[0][krow * 88 + kcol] = kreg;
  *(u16x8*)&sV[0][vrow * 40 + vcol] = vreg;
  __syncthreads();

#pragma unroll 1
  for (int pt = 0; pt < ntile; ++pt) {
    const int buf = pt & 1;
    const bool more = (pt + 1 < ntile);
    if (more) {  // prefetch next tile (overlaps this tile's compute)
      kreg = *(const u16x8*)&K[kg + (pt + 1) * 32 * 512];
      vreg = *(const u16x8*)&VT[vg + (pt + 1) * 32];
    }
    const unsigned short* bK = sK[buf];
    const unsigned short* bV = sV[buf];

    const bf16x8 ka0 = __builtin_bit_cast(bf16x8, *(const u16x8*)&bK[c * 88 + q * 8]);
    const bf16x8 ka1 = __builtin_bit_cast(bf16x8, *(const u16x8*)&bK[c * 88 + 32 + q * 8]);
    const bf16x8 kb0 = __builtin_bit_cast(bf16x8, *(const u16x8*)&bK[(16 + c) * 88 + q * 8]);
    const bf16x8 kb1 = __builtin_bit_cast(bf16x8, *(const u16x8*)&bK[(16 + c) * 88 + 32 + q * 8]);

    const f32x4 z = (f32x4){0.f, 0.f, 0.f, 0.f};
    f32x4 sA0 = mfma16(ka1, qfA1, mfma16(ka0, qfA0, z));  // patches p0+q*4+r
    f32x4 sA1 = mfma16(kb1, qfA1, mfma16(kb0, qfA0, z));  // patches p0+16+q*4+r
    f32x4 sB0 = mfma16(ka1, qfB1, mfma16(ka0, qfB0, z));
    f32x4 sB1 = mfma16(kb1, qfB1, mfma16(kb0, qfB0, z));

    if (pt + 1 == ntile) {  // only the last tile crosses the causal boundary
      const int p0 = pt * 32;
      const int limA = tA >> 2, limB = tB >> 2;
      const int pb0 = p0 + q * 4, pb1 = p0 + 16 + q * 4;
#pragma unroll
      for (int r = 0; r < 4; ++r) {
        if (pb0 + r > limA) sA0[r] = -1e30f;
        if (pb1 + r > limA) sA1[r] = -1e30f;
        if (pb0 + r > limB) sB0[r] = -1e30f;
        if (pb1 + r > limB) sB1[r] = -1e30f;
      }
    }

    float pA0[4], pA1[4], pB0[4], pB1[4];
#pragma unroll
    for (int r = 0; r < 4; ++r) {
      pA0[r] = fexp2(sA0[r]);
      pA1[r] = fexp2(sA1[r]);
      pB0[r] = fexp2(sB0[r]);
      pB1[r] = fexp2(sB1[r]);
    }

    // P -> per-wave LDS [token][patch], stride 40 (truncating pack)
    {
      u32x2 w;
      w[0] = packtr(pA0[0], pA0[1]); w[1] = packtr(pA0[2], pA0[3]);
      *(u32x2*)&sp[c * 40 + q * 4] = w;
      w[0] = packtr(pA1[0], pA1[1]); w[1] = packtr(pA1[2], pA1[3]);
      *(u32x2*)&sp[c * 40 + 16 + q * 4] = w;
      w[0] = packtr(pB0[0], pB0[1]); w[1] = packtr(pB0[2], pB0[3]);
      *(u32x2*)&sp[(16 + c) * 40 + q * 4] = w;
      w[0] = packtr(pB1[0], pB1[1]); w[1] = packtr(pB1[2], pB1[3]);
      *(u32x2*)&sp[(16 + c) * 40 + 16 + q * 4] = w;
    }
    const bf16x8 pbA = __builtin_bit_cast(bf16x8, *(const u16x8*)&sp[c * 40 + q * 8]);
    const bf16x8 pbB = __builtin_bit_cast(bf16x8, *(const u16x8*)&sp[(16 + c) * 40 + q * 8]);

    // ctx^T += V^T . P^T ; l += ones . P^T
#pragma unroll
    for (int mt = 0; mt < 4; ++mt) {
      const bf16x8 vf =
          __builtin_bit_cast(bf16x8, *(const u16x8*)&bV[(mt * 16 + c) * 40 + q * 8]);
      oA[mt] = mfma16(vf, pbA, oA[mt]);
      oB[mt] = mfma16(vf, pbB, oB[mt]);
    }
    lA = mfma16(ones, pbA, lA);
    lB = mfma16(ones, pbB, lB);

    if (more) {  // write next tile into the other buffer, single barrier
      *(u16x8*)&sK[buf ^ 1][krow * 88 + kcol] = kreg;
      *(u16x8*)&sV[buf ^ 1][vrow * 40 + vcol] = vreg;
      __syncthreads();
    }
  }

  const float invA = 1.f / lA[0];
  const float invB = 1.f / lB[0];
  const int obA = (b * TT + tA) * 512 + h * 64 + q * 4;
  const int obB = (b * TT + tB) * 512 + h * 64 + q * 4;
#pragma unroll
  for (int mt = 0; mt < 4; ++mt) {
    u16x4 oa, ob;
#pragma unroll
    for (int r = 0; r < 4; ++r) {
      oa[r] = f2bf(oA[mt][r] * invA);
      ob[r] = f2bf(oB[mt][r] * invB);
    }
    *(u16x4*)&CTX[obA + mt * 16] = oa;
    *(u16x4*)&CTX[obB + mt * 16] = ob;
  }
}

// ---------------------------------------------------------------------------
extern "C" void kernel_launch(void* const* d_in, const int* in_sizes, int n_in,
                              void* d_out, int out_size, void* d_ws, size_t ws_size,
                              hipStream_t stream) {
  const float* tok = (const float*)d_in[0];
  const float* pat = (const float*)d_in[1];
  const float* Wq = (const float*)d_in[2];
  const float* Wk = (const float*)d_in[3];
  const float* Wv = (const float*)d_in[4];
  const float* bq = (const float*)d_in[5];
  const float* bk = (const float*)d_in[6];
  const float* bv = (const float*)d_in[7];
  const float* Wo = (const float*)d_in[8];
  const float* bo = (const float*)d_in[9];
  float* out = (float*)d_out;

  unsigned short* ws = (unsigned short*)d_ws;
  unsigned short* WT = ws;                  // 4 x 512 x 512
  unsigned short* QB = ws + 2097152;        // 16384 x 512
  unsigned short* KB = ws + 10485760;       // 4096 x 512
  unsigned short* VTB = ws + 12582912;      // [4][512][1024]
  unsigned short* CTX = ws + 14680064;      // 16384 x 512   (ends 44 MB)

  k_wconv<<<1024, 256, 0, stream>>>(Wq, Wk, Wv, Wo, WT);
  k_gemm_qkv<<<768, 256, 0, stream>>>(tok, pat, WT, bq, bk, bv, QB, KB, VTB);
  k_attn<<<1024, 256, 0, stream>>>(QB, KB, VTB, CTX);
  k_gemm_o<<<512, 256, 0, stream>>>(CTX, WT + 786432, bo, out, tok);
}

// Round 11
// 194.300 us; speedup vs baseline: 1.2035x; 1.2035x over previous
//
#include <hip/hip_runtime.h>
#include <stdint.h>

// Problem constants
#define DM 512
#define NH 8
#define HDIM 64
#define TT 4096
#define PP 1024

typedef float f32x4 __attribute__((ext_vector_type(4)));
typedef __bf16 bf16x8 __attribute__((ext_vector_type(8)));
typedef unsigned short u16x8 __attribute__((ext_vector_type(8)));
typedef unsigned short u16x4 __attribute__((ext_vector_type(4)));
typedef unsigned int u32x2 __attribute__((ext_vector_type(2)));
typedef unsigned int u32x4 __attribute__((ext_vector_type(4)));

static __device__ __forceinline__ unsigned short f2bf(float f) {
  unsigned u = __builtin_bit_cast(unsigned, f);
  u += 0x7fff + ((u >> 16) & 1);  // RNE
  return (unsigned short)(u >> 16);
}

// truncating pack (for P: bias cancels in sum(Pv)/sum(P))
static __device__ __forceinline__ unsigned packtr(float a, float b) {
  return __builtin_amdgcn_perm(__builtin_bit_cast(unsigned, b),
                               __builtin_bit_cast(unsigned, a), 0x07060302u);
}

static __device__ __forceinline__ float fexp2(float x) {
#if __has_builtin(__builtin_amdgcn_exp2f)
  return __builtin_amdgcn_exp2f(x);
#else
  return __expf(x * 0.69314718055994531f);
#endif
}

static __device__ __forceinline__ void load_lds16(const void* g, void* l) {
  __builtin_amdgcn_global_load_lds(
      (__attribute__((address_space(1))) void*)g,
      (__attribute__((address_space(3))) void*)l, 16, 0, 0);
}

static __device__ __forceinline__ f32x4 mfma16(bf16x8 a, bf16x8 b, f32x4 c) {
  return __builtin_amdgcn_mfma_f32_16x16x32_bf16(a, b, c, 0, 0, 0);
}

// ---------------------------------------------------------------------------
// Convert: activations fp32 -> bf16 (straight); weights fp32 -> Wt[n][k] bf16.
// Cheap memory-bound kernel; removes the fp32-A tax from the GEMM loops.
// ---------------------------------------------------------------------------
__global__ __launch_bounds__(256) void k_conv(
    const float* __restrict__ tok, const float* __restrict__ pat,
    const float* __restrict__ wq, const float* __restrict__ wk,
    const float* __restrict__ wv, const float* __restrict__ wo,
    unsigned short* __restrict__ xtok, unsigned short* __restrict__ xpat,
    unsigned short* __restrict__ wt) {
  const int gid = blockIdx.x * 256 + threadIdx.x;
  const int NX = 2621440;  // (4*4096*512 + 4*1024*512) / 4
  if (gid < NX) {
    int i4 = gid * 4;
    const float* src;
    unsigned short* dst;
    int idx;
    if (i4 < 8388608) { src = tok; dst = xtok; idx = i4; }
    else              { src = pat; dst = xpat; idx = i4 - 8388608; }
    f32x4 v = *(const f32x4*)&src[idx];
    u16x4 o;
#pragma unroll
    for (int i = 0; i < 4; ++i) o[i] = f2bf(v[i]);
    *(u16x4*)&dst[idx] = o;
  } else {
    int wi = gid - NX;          // [0, 262144)
    int wid = wi >> 16;         // 0..3 -> q,k,v,o
    int e = (wi & 65535) << 2;  // element index k*512+n
    int k = e >> 9, n = e & 511;
    const float* w = (wid == 0) ? wq : (wid == 1) ? wk : (wid == 2) ? wv : wo;
    f32x4 v = *(const f32x4*)&w[e];
    unsigned short* wtb = wt + (wid << 18);
#pragma unroll
    for (int i = 0; i < 4; ++i) wtb[(n + i) * 512 + k] = f2bf(v[i]);
  }
}

// ---------------------------------------------------------------------------
// Projection GEMM, 128x128 tile, pure-DMA double-buffer (one barrier/K-iter):
// both A (bf16) and B staged via global_load_lds dwordx4. Zero VALU packs in
// the K-loop. Same structure as k_gemm_o (the fastest GEMM variant measured).
//   MODE 0: bf16 row-major (Q, scale folds 1/sqrt(HD) * log2(e))
//   MODE 1: bf16 row-major (K)
//   MODE 2: bf16 transposed to VT[b][n][p] (V)
// ---------------------------------------------------------------------------
template <int MODE>
__device__ __forceinline__ void gemm_bf16_body(
    const unsigned short* __restrict__ A, const unsigned short* __restrict__ Wt,
    const float* __restrict__ bias, unsigned short* __restrict__ outb,
    int bid, unsigned short* sA, unsigned short* sB, float scale) {
  const int tid = threadIdx.x;
  const int wave = tid >> 6, lane = tid & 63;
  const int q = lane >> 4, c = lane & 15;
  const int bm = bid >> 2, bn = bid & 3;
  const int wm = (wave >> 1) * 64, wn = (wave & 1) * 64;
  const int lr = lane >> 2, lc = (lane & 3) * 8;

  f32x4 acc[4][4];
#pragma unroll
  for (int i = 0; i < 4; ++i)
#pragma unroll
    for (int j = 0; j < 4; ++j) acc[i][j] = (f32x4){0.f, 0.f, 0.f, 0.f};

  const int rowA0 = bm * 128, rowB0 = bn * 128;

  // prologue: stage k=0 into buf 0
#pragma unroll
  for (int qq = 0; qq < 2; ++qq) {
    const int chunk = wave * 2 + qq;
    load_lds16(&A[(rowA0 + chunk * 16 + lr) * 512 + lc], &sA[chunk * 512]);
    load_lds16(&Wt[(rowB0 + chunk * 16 + lr) * 512 + lc], &sB[chunk * 512]);
  }
  __syncthreads();

#pragma unroll 1
  for (int i = 0; i < 16; ++i) {
    const int buf = i & 1;
    const unsigned short* curA = sA + buf * 4096;
    const unsigned short* curB = sB + buf * 4096;
    const bool more = (i < 15);
    if (more) {  // DMA k(i+1) into the other buffer (drains at next barrier)
      const int kn = (i + 1) * 32;
      unsigned short* nxtA = sA + (buf ^ 1) * 4096;
      unsigned short* nxtB = sB + (buf ^ 1) * 4096;
#pragma unroll
      for (int qq = 0; qq < 2; ++qq) {
        const int chunk = wave * 2 + qq;
        load_lds16(&A[(rowA0 + chunk * 16 + lr) * 512 + kn + lc], &nxtA[chunk * 512]);
        load_lds16(&Wt[(rowB0 + chunk * 16 + lr) * 512 + kn + lc], &nxtB[chunk * 512]);
      }
    }
    bf16x8 af[4], bfr[4];
#pragma unroll
    for (int mt = 0; mt < 4; ++mt)
      af[mt] = __builtin_bit_cast(bf16x8, *(const u16x8*)&curA[(wm + mt * 16 + c) * 32 + q * 8]);
#pragma unroll
    for (int nt = 0; nt < 4; ++nt)
      bfr[nt] = __builtin_bit_cast(bf16x8, *(const u16x8*)&curB[(wn + nt * 16 + c) * 32 + q * 8]);
#pragma unroll
    for (int mt = 0; mt < 4; ++mt)
#pragma unroll
      for (int nt = 0; nt < 4; ++nt)
        acc[mt][nt] = mfma16(af[mt], bfr[nt], acc[mt][nt]);
    if (more) __syncthreads();
  }

#pragma unroll
  for (int nt = 0; nt < 4; ++nt) {
    const int col = bn * 128 + wn + nt * 16 + c;
    const float bcol = bias[col];
#pragma unroll
    for (int mt = 0; mt < 4; ++mt) {
      const int row0 = bm * 128 + wm + mt * 16 + q * 4;
#pragma unroll
      for (int r = 0; r < 4; ++r) {
        const int row = row0 + r;
        const float v = (acc[mt][nt][r] + bcol) * scale;
        if (MODE == 2) {
          outb[((row >> 10) << 19) + (col << 10) + (row & 1023)] = f2bf(v);
        } else {
          outb[row * 512 + col] = f2bf(v);
        }
      }
    }
  }
}

__global__ __launch_bounds__(256) void k_gemm_qkv(
    const unsigned short* __restrict__ xtok, const unsigned short* __restrict__ xpat,
    const unsigned short* __restrict__ WT,
    const float* __restrict__ bq, const float* __restrict__ bk,
    const float* __restrict__ bv,
    unsigned short* __restrict__ QB, unsigned short* __restrict__ KB,
    unsigned short* __restrict__ VTB) {
  __shared__ unsigned short sA[2 * 128 * 32];
  __shared__ unsigned short sB[2 * 128 * 32];
  const int bid = blockIdx.x;
  if (bid < 512) {
    // scale = 0.125 * log2(e): scores come out in log2 domain for exp2
    gemm_bf16_body<0>(xtok, WT, bq, QB, bid, sA, sB, 0.18033688011112042f);
  } else if (bid < 640) {
    gemm_bf16_body<1>(xpat, WT + 262144, bk, KB, bid - 512, sA, sB, 1.0f);
  } else {
    gemm_bf16_body<2>(xpat, WT + 524288, bv, VTB, bid - 640, sA, sB, 1.0f);
  }
}

// ---------------------------------------------------------------------------
// Out-projection GEMM, 128x128, double-buffered DMA (one barrier per K-iter):
// out = CTX @ Wo + bo + resid (fp32).
// ---------------------------------------------------------------------------
__global__ __launch_bounds__(256) void k_gemm_o(
    const unsigned short* __restrict__ A, const unsigned short* __restrict__ Wt,
    const float* __restrict__ bias, float* __restrict__ outf,
    const float* __restrict__ resid) {
  __shared__ unsigned short sA[2 * 128 * 32];
  __shared__ unsigned short sB[2 * 128 * 32];
  const int tid = threadIdx.x;
  const int wave = tid >> 6, lane = tid & 63;
  const int q = lane >> 4, c = lane & 15;
  const int bm = blockIdx.x >> 2, bn = blockIdx.x & 3;
  const int wm = (wave >> 1) * 64, wn = (wave & 1) * 64;
  const int lr = lane >> 2, lc = (lane & 3) * 8;

  f32x4 acc[4][4];
#pragma unroll
  for (int i = 0; i < 4; ++i)
#pragma unroll
    for (int j = 0; j < 4; ++j) acc[i][j] = (f32x4){0.f, 0.f, 0.f, 0.f};

  const int rowA0 = bm * 128, rowB0 = bn * 128;

  // prologue: stage k=0 into buf 0
#pragma unroll
  for (int qq = 0; qq < 2; ++qq) {
    const int chunk = wave * 2 + qq;
    load_lds16(&A[(rowA0 + chunk * 16 + lr) * 512 + lc], &sA[chunk * 512]);
    load_lds16(&Wt[(rowB0 + chunk * 16 + lr) * 512 + lc], &sB[chunk * 512]);
  }
  __syncthreads();

#pragma unroll 1
  for (int i = 0; i < 16; ++i) {
    const int buf = i & 1;
    const unsigned short* curA = sA + buf * 4096;
    const unsigned short* curB = sB + buf * 4096;
    const bool more = (i < 15);
    if (more) {
      const int kn = (i + 1) * 32;
      unsigned short* nxtA = sA + (buf ^ 1) * 4096;
      unsigned short* nxtB = sB + (buf ^ 1) * 4096;
#pragma unroll
      for (int qq = 0; qq < 2; ++qq) {
        const int chunk = wave * 2 + qq;
        load_lds16(&A[(rowA0 + chunk * 16 + lr) * 512 + kn + lc], &nxtA[chunk * 512]);
        load_lds16(&Wt[(rowB0 + chunk * 16 + lr) * 512 + kn + lc], &nxtB[chunk * 512]);
      }
    }
    bf16x8 af[4], bfr[4];
#pragma unroll
    for (int mt = 0; mt < 4; ++mt)
      af[mt] = __builtin_bit_cast(bf16x8, *(const u16x8*)&curA[(wm + mt * 16 + c) * 32 + q * 8]);
#pragma unroll
    for (int nt = 0; nt < 4; ++nt)
      bfr[nt] = __builtin_bit_cast(bf16x8, *(const u16x8*)&curB[(wn + nt * 16 + c) * 32 + q * 8]);
#pragma unroll
    for (int mt = 0; mt < 4; ++mt)
#pragma unroll
      for (int nt = 0; nt < 4; ++nt)
        acc[mt][nt] = mfma16(af[mt], bfr[nt], acc[mt][nt]);
    if (more) __syncthreads();
  }

#pragma unroll
  for (int nt = 0; nt < 4; ++nt) {
    const int col = bn * 128 + wn + nt * 16 + c;
    const float bcol = bias[col];
#pragma unroll
    for (int mt = 0; mt < 4; ++mt) {
      const int row0 = bm * 128 + wm + mt * 16 + q * 4;
#pragma unroll
      for (int r = 0; r < 4; ++r) {
        const int row = row0 + r;
        const int o = row * 512 + col;
        outf[o] = acc[mt][nt][r] + bcol + resid[o];
      }
    }
  }
}

// ---------------------------------------------------------------------------
// Kernel 3: block-causal cross attention, no-max softmax in log2 domain.
// 1024 blocks, block = one (tg, b, h) unit (128 tokens), ntile = tg+1.
// Mapping g=bid>>5, tg = g<16 ? g : 47-g makes every stride-256 set
// {j, j+256, j+512, j+768} sum to exactly 66 tiles per CU (uniform);
// 4 blocks/CU = 16 waves/CU for latency hiding.
// ---------------------------------------------------------------------------
__global__ __launch_bounds__(256) void k_attn(
    const unsigned short* __restrict__ Q,   // [B*T][512], scaled by .125*log2e
    const unsigned short* __restrict__ K,   // [B*P][512]
    const unsigned short* __restrict__ VT,  // [B][512][1024]
    unsigned short* __restrict__ CTX) {     // [B*T][512]
  __shared__ unsigned short sK[2][32 * 88];
  __shared__ unsigned short sV[2][64 * 40];
  __shared__ unsigned short sPT[4][32 * 40];

  const int tid = threadIdx.x;
  const int lane = tid & 63;
  const int wave = tid >> 6;
  const int q = lane >> 4, c = lane & 15;

  const int g = blockIdx.x >> 5;               // [0,32)
  const int tg = (g < 16) ? g : 47 - g;        // uniform-per-CU mapping
  const int bh = blockIdx.x & 31;
  const int b = bh >> 3, h = bh & 7;
  const int t0 = tg * 128 + wave * 32;
  const int tA = t0 + c, tB = t0 + 16 + c;

  const int qbA = (b * TT + tA) * 512 + h * 64 + q * 8;
  const int qbB = (b * TT + tB) * 512 + h * 64 + q * 8;
  const bf16x8 qfA0 = __builtin_bit_cast(bf16x8, *(const u16x8*)&Q[qbA]);
  const bf16x8 qfA1 = __builtin_bit_cast(bf16x8, *(const u16x8*)&Q[qbA + 32]);
  const bf16x8 qfB0 = __builtin_bit_cast(bf16x8, *(const u16x8*)&Q[qbB]);
  const bf16x8 qfB1 = __builtin_bit_cast(bf16x8, *(const u16x8*)&Q[qbB + 32]);

  f32x4 oA[4], oB[4];
#pragma unroll
  for (int m = 0; m < 4; ++m) {
    oA[m] = (f32x4){0.f, 0.f, 0.f, 0.f};
    oB[m] = (f32x4){0.f, 0.f, 0.f, 0.f};
  }
  f32x4 lA = (f32x4){0.f, 0.f, 0.f, 0.f};
  f32x4 lB = lA;
  const u16x8 onesu = {0x3F80, 0x3F80, 0x3F80, 0x3F80, 0x3F80, 0x3F80, 0x3F80, 0x3F80};
  const bf16x8 ones = __builtin_bit_cast(bf16x8, onesu);

  const int ntile = tg + 1;
  const int krow = tid >> 3, kcol = (tid & 7) * 8;
  const int vrow = tid >> 2, vcol = (tid & 3) * 8;
  const int kg = (b * PP + krow) * 512 + h * 64 + kcol;
  const int vg = (b << 19) + ((h * 64 + vrow) << 10) + vcol;
  unsigned short* sp = sPT[wave];

  // stage tile 0
  u16x8 kreg = *(const u16x8*)&K[kg];
  u16x8 vreg = *(const u16x8*)&VT[vg];
  *(u16x8*)&sK[0][krow * 88 + kcol] = kreg;
  *(u16x8*)&sV[0][vrow * 40 + vcol] = vreg;
  __syncthreads();

#pragma unroll 1
  for (int pt = 0; pt < ntile; ++pt) {
    const int buf = pt & 1;
    const bool more = (pt + 1 < ntile);
    if (more) {  // prefetch next tile (overlaps this tile's compute)
      kreg = *(const u16x8*)&K[kg + (pt + 1) * 32 * 512];
      vreg = *(const u16x8*)&VT[vg + (pt + 1) * 32];
    }
    const unsigned short* bK = sK[buf];
    const unsigned short* bV = sV[buf];

    const bf16x8 ka0 = __builtin_bit_cast(bf16x8, *(const u16x8*)&bK[c * 88 + q * 8]);
    const bf16x8 ka1 = __builtin_bit_cast(bf16x8, *(const u16x8*)&bK[c * 88 + 32 + q * 8]);
    const bf16x8 kb0 = __builtin_bit_cast(bf16x8, *(const u16x8*)&bK[(16 + c) * 88 + q * 8]);
    const bf16x8 kb1 = __builtin_bit_cast(bf16x8, *(const u16x8*)&bK[(16 + c) * 88 + 32 + q * 8]);

    const f32x4 z = (f32x4){0.f, 0.f, 0.f, 0.f};
    f32x4 sA0 = mfma16(ka1, qfA1, mfma16(ka0, qfA0, z));  // patches p0+q*4+r
    f32x4 sA1 = mfma16(kb1, qfA1, mfma16(kb0, qfA0, z));  // patches p0+16+q*4+r
    f32x4 sB0 = mfma16(ka1, qfB1, mfma16(ka0, qfB0, z));
    f32x4 sB1 = mfma16(kb1, qfB1, mfma16(kb0, qfB0, z));

    if (pt + 1 == ntile) {  // only the last tile crosses the causal boundary
      const int p0 = pt * 32;
      const int limA = tA >> 2, limB = tB >> 2;
      const int pb0 = p0 + q * 4, pb1 = p0 + 16 + q * 4;
#pragma unroll
      for (int r = 0; r < 4; ++r) {
        if (pb0 + r > limA) sA0[r] = -1e30f;
        if (pb1 + r > limA) sA1[r] = -1e30f;
        if (pb0 + r > limB) sB0[r] = -1e30f;
        if (pb1 + r > limB) sB1[r] = -1e30f;
      }
    }

    float pA0[4], pA1[4], pB0[4], pB1[4];
#pragma unroll
    for (int r = 0; r < 4; ++r) {
      pA0[r] = fexp2(sA0[r]);
      pA1[r] = fexp2(sA1[r]);
      pB0[r] = fexp2(sB0[r]);
      pB1[r] = fexp2(sB1[r]);
    }

    // P -> per-wave LDS [token][patch], stride 40 (truncating pack)
    {
      u32x2 w;
      w[0] = packtr(pA0[0], pA0[1]); w[1] = packtr(pA0[2], pA0[3]);
      *(u32x2*)&sp[c * 40 + q * 4] = w;
      w[0] = packtr(pA1[0], pA1[1]); w[1] = packtr(pA1[2], pA1[3]);
      *(u32x2*)&sp[c * 40 + 16 + q * 4] = w;
      w[0] = packtr(pB0[0], pB0[1]); w[1] = packtr(pB0[2], pB0[3]);
      *(u32x2*)&sp[(16 + c) * 40 + q * 4] = w;
      w[0] = packtr(pB1[0], pB1[1]); w[1] = packtr(pB1[2], pB1[3]);
      *(u32x2*)&sp[(16 + c) * 40 + 16 + q * 4] = w;
    }
    const bf16x8 pbA = __builtin_bit_cast(bf16x8, *(const u16x8*)&sp[c * 40 + q * 8]);
    const bf16x8 pbB = __builtin_bit_cast(bf16x8, *(const u16x8*)&sp[(16 + c) * 40 + q * 8]);

    // ctx^T += V^T . P^T ; l += ones . P^T
#pragma unroll
    for (int mt = 0; mt < 4; ++mt) {
      const bf16x8 vf =
          __builtin_bit_cast(bf16x8, *(const u16x8*)&bV[(mt * 16 + c) * 40 + q * 8]);
      oA[mt] = mfma16(vf, pbA, oA[mt]);
      oB[mt] = mfma16(vf, pbB, oB[mt]);
    }
    lA = mfma16(ones, pbA, lA);
    lB = mfma16(ones, pbB, lB);

    if (more) {  // write next tile into the other buffer, single barrier
      *(u16x8*)&sK[buf ^ 1][krow * 88 + kcol] = kreg;
      *(u16x8*)&sV[buf ^ 1][vrow * 40 + vcol] = vreg;
      __syncthreads();
    }
  }

  const float invA = 1.f / lA[0];
  const float invB = 1.f / lB[0];
  const int obA = (b * TT + tA) * 512 + h * 64 + q * 4;
  const int obB = (b * TT + tB) * 512 + h * 64 + q * 4;
#pragma unroll
  for (int mt = 0; mt < 4; ++mt) {
    u16x4 oa, ob;
#pragma unroll
    for (int r = 0; r < 4; ++r) {
      oa[r] = f2bf(oA[mt][r] * invA);
      ob[r] = f2bf(oB[mt][r] * invB);
    }
    *(u16x4*)&CTX[obA + mt * 16] = oa;
    *(u16x4*)&CTX[obB + mt * 16] = ob;
  }
}

// ---------------------------------------------------------------------------
extern "C" void kernel_launch(void* const* d_in, const int* in_sizes, int n_in,
                              void* d_out, int out_size, void* d_ws, size_t ws_size,
                              hipStream_t stream) {
  const float* tok = (const float*)d_in[0];
  const float* pat = (const float*)d_in[1];
  const float* Wq = (const float*)d_in[2];
  const float* Wk = (const float*)d_in[3];
  const float* Wv = (const float*)d_in[4];
  const float* bq = (const float*)d_in[5];
  const float* bk = (const float*)d_in[6];
  const float* bv = (const float*)d_in[7];
  const float* Wo = (const float*)d_in[8];
  const float* bo = (const float*)d_in[9];
  float* out = (float*)d_out;

  unsigned short* ws = (unsigned short*)d_ws;
  unsigned short* WT = ws;                   // 4 x 512 x 512
  unsigned short* XTOK = ws + 1048576;       // 16384 x 512 bf16
  unsigned short* XPAT = ws + 9437184;       // 4096 x 512 bf16
  unsigned short* QB = ws + 11534336;        // 16384 x 512
  unsigned short* KB = ws + 19922944;        // 4096 x 512
  unsigned short* VTB = ws + 22020096;       // [4][512][1024]
  unsigned short* CTX = ws + 24117248;       // 16384 x 512   (ends 65 MB)

  k_conv<<<11264, 256, 0, stream>>>(tok, pat, Wq, Wk, Wv, Wo, XTOK, XPAT, WT);
  k_gemm_qkv<<<768, 256, 0, stream>>>(XTOK, XPAT, WT, bq, bk, bv, QB, KB, VTB);
  k_attn<<<1024, 256, 0, stream>>>(QB, KB, VTB, CTX);
  k_gemm_o<<<512, 256, 0, stream>>>(CTX, WT + 786432, bo, out, tok);
}